// Round 5
// baseline (46552.094 us; speedup 1.0000x reference)
//
#include <hip/hip_runtime.h>
#include <hip/hip_bf16.h>
#include <math.h>

#define B_  2048
#define S_  128
#define H_  512
#define K_  16
#define NSTEP 63
#define GRID 512

typedef __bf16 bf16x8 __attribute__((ext_vector_type(8)));
typedef float  f32x4  __attribute__((ext_vector_type(4)));
typedef unsigned short u16x8 __attribute__((ext_vector_type(8)));

static __device__ __forceinline__ void f2b2(float v, unsigned short& hi, unsigned short& lo)
{
    __hip_bfloat16 h = __float2bfloat16(v);
    float r = v - __bfloat162float(h);
    __hip_bfloat16 l = __float2bfloat16(r);
    hi = __builtin_bit_cast(unsigned short, h);
    lo = __builtin_bit_cast(unsigned short, l);
}

static __device__ __forceinline__ void gl16(const unsigned short* g, unsigned short* l)
{
    __builtin_amdgcn_global_load_lds(
        (const __attribute__((address_space(1))) unsigned int*)g,
        (__attribute__((address_space(3))) unsigned int*)l, 16, 0, 0);
}

// device-scope grid barrier: one counter per barrier instance, monotonic (zeroed per call)
static __device__ __forceinline__ void gbar(unsigned int* c, unsigned int target)
{
    __syncthreads();
    if (threadIdx.x == 0) {
        __threadfence();
        __hip_atomic_fetch_add(c, 1u, __ATOMIC_RELEASE, __HIP_MEMORY_SCOPE_AGENT);
        while (__hip_atomic_load(c, __ATOMIC_ACQUIRE, __HIP_MEMORY_SCOPE_AGENT) < target)
            __builtin_amdgcn_s_sleep(2);
        __threadfence();
    }
    __syncthreads();
}

// ---- GEMM tile: BM=64, BK=64, BN in {64,128}; 4 waves 2x2 (WM=32, WN=BN/2).
// A pre-offset by rowBase*lda; W pre-transposed [N][K] pre-offset by colBase*K.
// LDS planes [Ah|Al|Bh|Bl]; A plane 64x64, B plane BNx64; 16B chunks linear in load order.
// 3-MFMA split: ah*bh + ah*bl + al*bh, f32 accum.
template<int BN>
static __device__ __forceinline__ void gemm_tile(
    unsigned short* lds,
    const unsigned short* __restrict__ Ahi, const unsigned short* __restrict__ Alo, int lda,
    const unsigned short* __restrict__ Whi, const unsigned short* __restrict__ Wlo, int Kd,
    f32x4 (&acc)[2][BN/32])
{
    constexpr int NJ = BN/32, WN = BN/2;
    constexpr int PLA = 64*64, PLB = BN*64;
    unsigned short* Ah = lds;
    unsigned short* Al = lds + PLA;
    unsigned short* Bh = lds + 2*PLA;
    unsigned short* Bl = lds + 2*PLA + PLB;

    const int tid = threadIdx.x, lane = tid & 63;
    const int wid = tid >> 6, wr = wid >> 1, wc = wid & 1;
    const int r16 = lane & 15, kg = lane >> 4;
    const int ub = tid & ~63;

    for (int k0 = 0; k0 < Kd; k0 += 64) {
#pragma unroll
        for (int c0 = 0; c0 < 512; c0 += 256) {       // A: 64 rows x 8 kgroups
            int c = c0 + tid;
            int row = c & 63, g = c >> 6;
            size_t off = (size_t)row * lda + k0 + g*8;
            gl16(Ahi + off, Ah + (size_t)(c0 + ub)*8);
            gl16(Alo + off, Al + (size_t)(c0 + ub)*8);
        }
#pragma unroll
        for (int c0 = 0; c0 < BN*8; c0 += 256) {      // B: BN rows x 8 kgroups
            int c = c0 + tid;
            int row = c & (BN-1), g = c / BN;
            size_t off = (size_t)row * Kd + k0 + g*8;
            gl16(Whi + off, Bh + (size_t)(c0 + ub)*8);
            gl16(Wlo + off, Bl + (size_t)(c0 + ub)*8);
        }
        __syncthreads();
#pragma unroll
        for (int kk = 0; kk < 2; ++kk) {
            bf16x8 a_h[2], a_l[2], b_h[NJ], b_l[NJ];
#pragma unroll
            for (int i = 0; i < 2; ++i) {
                int ch = (kk*4 + kg)*64 + wr*32 + i*16 + r16;
                a_h[i] = __builtin_bit_cast(bf16x8, *(const u16x8*)(Ah + (size_t)ch*8));
                a_l[i] = __builtin_bit_cast(bf16x8, *(const u16x8*)(Al + (size_t)ch*8));
            }
#pragma unroll
            for (int j = 0; j < NJ; ++j) {
                int ch = (kk*4 + kg)*BN + wc*WN + j*16 + r16;
                b_h[j] = __builtin_bit_cast(bf16x8, *(const u16x8*)(Bh + (size_t)ch*8));
                b_l[j] = __builtin_bit_cast(bf16x8, *(const u16x8*)(Bl + (size_t)ch*8));
            }
#pragma unroll
            for (int i = 0; i < 2; ++i)
#pragma unroll
                for (int j = 0; j < NJ; ++j) {
                    acc[i][j] = __builtin_amdgcn_mfma_f32_16x16x32_bf16(a_h[i], b_h[j], acc[i][j], 0, 0, 0);
                    acc[i][j] = __builtin_amdgcn_mfma_f32_16x16x32_bf16(a_h[i], b_l[j], acc[i][j], 0, 0, 0);
                    acc[i][j] = __builtin_amdgcn_mfma_f32_16x16x32_bf16(a_l[i], b_h[j], acc[i][j], 0, 0, 0);
                }
        }
        __syncthreads();
    }
}

// persistent whole-SDE kernel. grid=512 blocks x 256 thr, all resident (48KB LDS, VGPR<=256).
// C/D frag: col = lane&15, row = (lane>>4)*4 + reg.
__global__ __launch_bounds__(256, 2) void sde_k(
    const float* __restrict__ ts,
    const float* __restrict__ dW,
    const float* __restrict__ g_w1, const float* __restrict__ g_b1,
    const float* __restrict__ f_w1, const float* __restrict__ f_b1,
    const float* __restrict__ f_b2, const float* __restrict__ f_b3,
    const float* __restrict__ g_b2,
    const unsigned short* __restrict__ w1tH, const unsigned short* __restrict__ w1tL,
    const unsigned short* __restrict__ gw2H, const unsigned short* __restrict__ gw2L,
    const unsigned short* __restrict__ fw2H, const unsigned short* __restrict__ fw2L,
    const unsigned short* __restrict__ fw3H, const unsigned short* __restrict__ fw3L,
    unsigned short* __restrict__ HAh, unsigned short* __restrict__ HAl,
    unsigned short* __restrict__ HBh, unsigned short* __restrict__ HBl,
    unsigned short* __restrict__ ytH, unsigned short* __restrict__ ytL,
    unsigned short* __restrict__ ycH, unsigned short* __restrict__ ycL,
    float* __restrict__ gp, float* __restrict__ drift,
    float* __restrict__ out,
    unsigned int* __restrict__ ctrs)
{
    __shared__ __align__(16) unsigned short lds[2*64*64 + 2*128*64];
    const int bid = blockIdx.x;
    const int tid = threadIdx.x, l = tid & 63, wid = tid >> 6;
    const int wr = wid >> 1, wc = wid & 1, r16 = l & 15, rg = l >> 4;
    const unsigned int tgt = gridDim.x;
    // XCD-friendly strip mapping for 512-tile phases: 64 blocks per XCD cover 2 strips
    const int q = bid >> 3;
    const int strip512 = (bid & 7)*2 + (q >> 5);   // 0..15
    const int rowb512  = q & 31;                   // 0..31

    for (int step = 0; step < NSTEP; ++step) {
        const float* y  = out + (size_t)step * B_ * S_;
        float*       y1 = out + (size_t)(step+1) * B_ * S_;
        const float* dWs = dW + (size_t)step * B_ * K_;
        const float tcur = ts[3+step];
        const float dt   = ts[4+step] - tcur;
        const float sq   = sqrtf(dt);

        // ---- P1: HA = relu([t,yc] @ [g_w1|f_w1]) (2048x1024), 512 tiles 64x64
        {
            const int rowBase = rowb512*64, colBase = strip512*64;
            f32x4 acc[2][2] = {};
            gemm_tile<64>(lds, ycH + (size_t)rowBase*S_, ycL + (size_t)rowBase*S_, S_,
                          w1tH + (size_t)colBase*128, w1tL + (size_t)colBase*128, 128, acc);
#pragma unroll
            for (int j = 0; j < 2; ++j) {
                int colj = colBase + wc*32 + j*16 + r16;
                float be = (colj < 512) ? (g_b1[colj] + tcur*g_w1[colj])
                                        : (f_b1[colj-512] + tcur*f_w1[colj-512]);
#pragma unroll
                for (int i = 0; i < 2; ++i)
#pragma unroll
                    for (int reg = 0; reg < 4; ++reg) {
                        int row = rowBase + wr*32 + i*16 + rg*4 + reg;
                        float v = fmaxf(acc[i][j][reg] + be, 0.f);
                        unsigned short h, lo; f2b2(v, h, lo);
                        size_t o = (size_t)row*1024 + colj;
                        HAh[o] = h; HAl[o] = lo;
                    }
            }
        }
        gbar(ctrs + step*4 + 0, tgt);

        // ---- P2: 512 g-tiles (64x128, K=512): gp + ytmp; 128 f-tiles: HB = relu(HA_f@f_w2+b)
        for (int t = bid; t < 640; t += GRID) {
            if (t < 512) {
                const int rowBase = rowb512*64, colBase = strip512*128;
                f32x4 acc[2][4] = {};
                gemm_tile<128>(lds, HAh + (size_t)rowBase*1024, HAl + (size_t)rowBase*1024, 1024,
                               gw2H + (size_t)colBase*H_, gw2L + (size_t)colBase*H_, H_, acc);
#pragma unroll
                for (int i = 0; i < 2; ++i)
#pragma unroll
                    for (int reg = 0; reg < 4; ++reg) {
                        int row = rowBase + wr*32 + i*16 + rg*4 + reg;
                        float dwv = dWs[row*K_ + r16] * sq;
#pragma unroll
                        for (int j = 0; j < 4; ++j) {
                            int colj = colBase + wc*64 + j*16;
                            float m = (acc[i][j][reg] + g_b2[colj + r16]) * dwv;
                            m += __shfl_xor(m,1); m += __shfl_xor(m,2);
                            m += __shfl_xor(m,4); m += __shfl_xor(m,8);
                            if (r16 == 0) {
                                int idx = row*S_ + (colj>>4);
                                gp[idx] = m;
                                unsigned short h, lo; f2b2(y[idx] + m, h, lo);
                                ytH[idx] = h; ytL[idx] = lo;
                            }
                        }
                    }
            } else {
                const int u = t - 512;                  // 0..127
                const int rowBase = (u & 31)*64, colBase = (u >> 5)*128;
                f32x4 acc[2][4] = {};
                gemm_tile<128>(lds, HAh + (size_t)rowBase*1024 + 512, HAl + (size_t)rowBase*1024 + 512, 1024,
                               fw2H + (size_t)colBase*H_, fw2L + (size_t)colBase*H_, H_, acc);
#pragma unroll
                for (int j = 0; j < 4; ++j) {
                    int colj = colBase + wc*64 + j*16 + r16;
                    float be = f_b2[colj];
#pragma unroll
                    for (int i = 0; i < 2; ++i)
#pragma unroll
                        for (int reg = 0; reg < 4; ++reg) {
                            int row = rowBase + wr*32 + i*16 + rg*4 + reg;
                            float v = fmaxf(acc[i][j][reg] + be, 0.f);
                            unsigned short h, lo; f2b2(v, h, lo);
                            size_t o = (size_t)row*512 + colj;
                            HBh[o] = h; HBl[o] = lo;
                        }
                }
            }
        }
        gbar(ctrs + step*4 + 1, tgt);

        // ---- P3: 256 tiles HA2 = relu([t,yt]@g_w1+b) (64x64); 64 tiles drift = HB@f_w3+b (64x64)
        if (bid < 320) {
            if (bid < 256) {
                const int rowBase = (bid & 31)*64, colBase = (bid >> 5)*64;
                f32x4 acc[2][2] = {};
                gemm_tile<64>(lds, ytH + (size_t)rowBase*S_, ytL + (size_t)rowBase*S_, S_,
                              w1tH + (size_t)colBase*128, w1tL + (size_t)colBase*128, 128, acc);
#pragma unroll
                for (int j = 0; j < 2; ++j) {
                    int colj = colBase + wc*32 + j*16 + r16;
                    float be = g_b1[colj] + tcur*g_w1[colj];
#pragma unroll
                    for (int i = 0; i < 2; ++i)
#pragma unroll
                        for (int reg = 0; reg < 4; ++reg) {
                            int row = rowBase + wr*32 + i*16 + rg*4 + reg;
                            float v = fmaxf(acc[i][j][reg] + be, 0.f);
                            unsigned short h, lo; f2b2(v, h, lo);
                            size_t o = (size_t)row*512 + colj;
                            // HA2 aliases HA (HA_g dead after P2) -- store at ld 512
                            HAh[o] = h; HAl[o] = lo;
                        }
                }
            } else {
                const int u = bid - 256;                // 0..63
                const int rowBase = (u & 31)*64, colBase = (u >> 5)*64;
                f32x4 acc[2][2] = {};
                gemm_tile<64>(lds, HBh + (size_t)rowBase*H_, HBl + (size_t)rowBase*H_, H_,
                              fw3H + (size_t)colBase*H_, fw3L + (size_t)colBase*H_, H_, acc);
#pragma unroll
                for (int j = 0; j < 2; ++j) {
                    int colj = colBase + wc*32 + j*16 + r16;
                    float be = f_b3[colj];
#pragma unroll
                    for (int i = 0; i < 2; ++i)
#pragma unroll
                        for (int reg = 0; reg < 4; ++reg) {
                            int row = rowBase + wr*32 + i*16 + rg*4 + reg;
                            drift[row*S_ + colj] = acc[i][j][reg] + be;
                        }
                }
            }
        }
        gbar(ctrs + step*4 + 2, tgt);

        // ---- P4: 512 g-tiles: gp2 + final update -> y1 (f32) + yc (hi/lo)
        {
            const int rowBase = rowb512*64, colBase = strip512*128;
            f32x4 acc[2][4] = {};
            gemm_tile<128>(lds, HAh + (size_t)rowBase*512, HAl + (size_t)rowBase*512, 512,
                           gw2H + (size_t)colBase*H_, gw2L + (size_t)colBase*H_, H_, acc);
#pragma unroll
            for (int i = 0; i < 2; ++i)
#pragma unroll
                for (int reg = 0; reg < 4; ++reg) {
                    int row = rowBase + wr*32 + i*16 + rg*4 + reg;
                    float dwv = dWs[row*K_ + r16] * sq;
#pragma unroll
                    for (int j = 0; j < 4; ++j) {
                        int colj = colBase + wc*64 + j*16;
                        float m = (acc[i][j][reg] + g_b2[colj + r16]) * dwv;
                        m += __shfl_xor(m,1); m += __shfl_xor(m,2);
                        m += __shfl_xor(m,4); m += __shfl_xor(m,8);
                        if (r16 == 0) {
                            int idx = row*S_ + (colj>>4);
                            float v1 = y[idx] + drift[idx]*dt + 0.5f*(gp[idx] + m);
                            y1[idx] = v1;
                            unsigned short h, lo; f2b2(v1, h, lo);
                            ycH[idx] = h; ycL[idx] = lo;
                        }
                    }
                }
        }
        gbar(ctrs + step*4 + 3, tgt);
    }
}

__global__ __launch_bounds__(256) void tcast_k(
    const float* __restrict__ in, int rowOff, int Kd, int N,
    unsigned short* __restrict__ outH, unsigned short* __restrict__ outL)
{
    __shared__ float tl[32][33];
    const int kb = blockIdx.x*32, nb = blockIdx.y*32;
    const int tx = threadIdx.x, ty = threadIdx.y;
    for (int r = ty; r < 32; r += 8)
        tl[r][tx] = in[(size_t)(rowOff + kb + r)*N + nb + tx];
    __syncthreads();
    for (int r = ty; r < 32; r += 8) {
        unsigned short h, lo; f2b2(tl[tx][r], h, lo);
        size_t o = (size_t)(nb + r)*Kd + kb + tx;
        outH[o] = h; outL[o] = lo;
    }
}

__global__ __launch_bounds__(128) void encoder_k(
    const float* __restrict__ x,
    const float* __restrict__ w1, const float* __restrict__ b1,
    const float* __restrict__ w2, const float* __restrict__ b2,
    float* __restrict__ y0,
    unsigned short* __restrict__ ycH, unsigned short* __restrict__ ycL)
{
    int b = blockIdx.x;
    __shared__ float h[H_];
    int tid = threadIdx.x;
    float x0 = x[b*3+0], x1 = x[b*3+1], x2 = x[b*3+2];
    for (int i = tid; i < H_; i += 128)
        h[i] = fmaxf(x0*w1[i] + x1*w1[H_+i] + x2*w1[2*H_+i] + b1[i], 0.f);
    __syncthreads();
    float acc = b2[tid];
    for (int k = 0; k < H_; ++k) acc += h[k]*w2[k*S_+tid];
    size_t o = (size_t)b*S_ + tid;
    y0[o] = acc;
    unsigned short hh, ll; f2b2(acc, hh, ll);
    ycH[o] = hh; ycL[o] = ll;
}

__global__ void zero_ctr_k(unsigned int* c) { c[threadIdx.x] = 0; }

extern "C" void kernel_launch(void* const* d_in, const int* in_sizes, int n_in,
                              void* d_out, int out_size, void* d_ws, size_t ws_size,
                              hipStream_t stream)
{
    const float* ts     = (const float*)d_in[0];
    const float* x      = (const float*)d_in[1];
    const float* enc_w1 = (const float*)d_in[2];
    const float* enc_b1 = (const float*)d_in[3];
    const float* enc_w2 = (const float*)d_in[4];
    const float* enc_b2 = (const float*)d_in[5];
    const float* f_w1   = (const float*)d_in[6];
    const float* f_b1   = (const float*)d_in[7];
    const float* f_w2   = (const float*)d_in[8];
    const float* f_b2   = (const float*)d_in[9];
    const float* f_w3   = (const float*)d_in[10];
    const float* f_b3   = (const float*)d_in[11];
    const float* g_w1   = (const float*)d_in[12];
    const float* g_b1   = (const float*)d_in[13];
    const float* g_w2   = (const float*)d_in[14];
    const float* g_b2   = (const float*)d_in[15];
    const float* dW     = (const float*)d_in[16];

    float* out = (float*)d_out;
    unsigned short* w = (unsigned short*)d_ws;

    unsigned short* w1tH  = w;                      // 1024*128
    unsigned short* w1tL  = w1tH  + 1024*128;
    unsigned short* gw2H  = w1tL  + 1024*128;       // 2048*512
    unsigned short* gw2L  = gw2H  + 2048*512;
    unsigned short* fw2H  = gw2L  + 2048*512;       // 512*512
    unsigned short* fw2L  = fw2H  + 512*512;
    unsigned short* fw3H  = fw2L  + 512*512;        // 128*512
    unsigned short* fw3L  = fw3H  + 128*512;
    unsigned short* HAh   = fw3L  + 128*512;        // 2048*1024
    unsigned short* HAl   = HAh   + 2048*1024;
    unsigned short* HBh   = HAl   + 2048*1024;      // 2048*512
    unsigned short* HBl   = HBh   + 2048*512;
    unsigned short* ytH   = HBl   + 2048*512;       // 2048*128
    unsigned short* ytL   = ytH   + 2048*128;
    unsigned short* ycH   = ytL   + 2048*128;       // 2048*128
    unsigned short* ycL   = ycH   + 2048*128;
    float* gp    = (float*)(ycL + 2048*128);        // 2048*128 f32
    float* drift = gp + 2048*128;                   // 2048*128 f32
    unsigned int* ctrs = (unsigned int*)(drift + 2048*128);  // 256 uints

    dim3 tb(32,8);
    tcast_k<<<dim3(4,16),  tb, 0, stream>>>(g_w1, 1, 128, 512,  w1tH,          w1tL);
    tcast_k<<<dim3(4,16),  tb, 0, stream>>>(f_w1, 1, 128, 512,  w1tH+512*128,  w1tL+512*128);
    tcast_k<<<dim3(16,16), tb, 0, stream>>>(f_w2, 0, 512, 512,  fw2H,          fw2L);
    tcast_k<<<dim3(16,4),  tb, 0, stream>>>(f_w3, 0, 512, 128,  fw3H,          fw3L);
    tcast_k<<<dim3(16,64), tb, 0, stream>>>(g_w2, 0, 512, 2048, gw2H,          gw2L);

    encoder_k<<<B_, 128, 0, stream>>>(x, enc_w1, enc_b1, enc_w2, enc_b2, out, ycH, ycL);
    zero_ctr_k<<<1, 256, 0, stream>>>(ctrs);

    sde_k<<<GRID, 256, 0, stream>>>(
        ts, dW, g_w1, g_b1, f_w1, f_b1, f_b2, f_b3, g_b2,
        w1tH, w1tL, gw2H, gw2L, fw2H, fw2L, fw3H, fw3L,
        HAh, HAl, HBh, HBl, ytH, ytL, ycH, ycL,
        gp, drift, out, ctrs);
}

// Round 6
// 29340.817 us; speedup vs baseline: 1.5866x; 1.5866x over previous
//
#include <hip/hip_runtime.h>
#include <hip/hip_bf16.h>
#include <math.h>

#define B_  2048
#define S_  128
#define H_  512
#define K_  16
#define NSTEP 63
#define GRID 512

typedef __bf16 bf16x8 __attribute__((ext_vector_type(8)));
typedef float  f32x4  __attribute__((ext_vector_type(4)));
typedef unsigned short u16x8 __attribute__((ext_vector_type(8)));

static __device__ __forceinline__ void f2b2(float v, unsigned short& hi, unsigned short& lo)
{
    __hip_bfloat16 h = __float2bfloat16(v);
    float r = v - __bfloat162float(h);
    __hip_bfloat16 l = __float2bfloat16(r);
    hi = __builtin_bit_cast(unsigned short, h);
    lo = __builtin_bit_cast(unsigned short, l);
}

static __device__ __forceinline__ void gl16(const unsigned short* g, unsigned short* l)
{
    __builtin_amdgcn_global_load_lds(
        (const __attribute__((address_space(1))) unsigned int*)g,
        (__attribute__((address_space(3))) unsigned int*)l, 16, 0, 0);
}

// device-scope grid barrier, FIXED fences:
//  - arrival: one RELEASE fetch_add per block (single wbl2 -> makes this block's writes visible)
//  - poll: RELAXED agent loads (bypass non-coherent caches, NO buffer_inv per iteration)
//  - exit: one ACQUIRE load (single buffer_inv -> this CU sees remote writes)
//  - liveness hedge: ACQUIRE poll every 256 spins
static __device__ __forceinline__ void gbar(unsigned int* c, unsigned int target)
{
    __syncthreads();
    if (threadIdx.x == 0) {
        __hip_atomic_fetch_add(c, 1u, __ATOMIC_RELEASE, __HIP_MEMORY_SCOPE_AGENT);
        int spins = 0;
        while (true) {
            unsigned int v = ((++spins & 255) == 0)
                ? __hip_atomic_load(c, __ATOMIC_ACQUIRE, __HIP_MEMORY_SCOPE_AGENT)
                : __hip_atomic_load(c, __ATOMIC_RELAXED, __HIP_MEMORY_SCOPE_AGENT);
            if (v >= target) break;
            __builtin_amdgcn_s_sleep(4);
        }
        (void)__hip_atomic_load(c, __ATOMIC_ACQUIRE, __HIP_MEMORY_SCOPE_AGENT);
    }
    __syncthreads();
}

// ---- GEMM tile: BM=64, BK=64, BN in {64,128}; 4 waves 2x2 (WM=32, WN=BN/2).
// A pre-offset by rowBase*lda; W pre-transposed [N][K] pre-offset by colBase*K.
// LDS planes [Ah|Al|Bh|Bl]; 16B chunks linear in load order.
// 3-MFMA split: ah*bh + ah*bl + al*bh, f32 accum.
template<int BN>
static __device__ __forceinline__ void gemm_tile(
    unsigned short* lds,
    const unsigned short* __restrict__ Ahi, const unsigned short* __restrict__ Alo, int lda,
    const unsigned short* __restrict__ Whi, const unsigned short* __restrict__ Wlo, int Kd,
    f32x4 (&acc)[2][BN/32])
{
    constexpr int NJ = BN/32, WN = BN/2;
    constexpr int PLA = 64*64, PLB = BN*64;
    unsigned short* Ah = lds;
    unsigned short* Al = lds + PLA;
    unsigned short* Bh = lds + 2*PLA;
    unsigned short* Bl = lds + 2*PLA + PLB;

    const int tid = threadIdx.x, lane = tid & 63;
    const int wid = tid >> 6, wr = wid >> 1, wc = wid & 1;
    const int r16 = lane & 15, kg = lane >> 4;
    const int ub = tid & ~63;

    for (int k0 = 0; k0 < Kd; k0 += 64) {
#pragma unroll
        for (int c0 = 0; c0 < 512; c0 += 256) {       // A: 64 rows x 8 kgroups
            int c = c0 + tid;
            int row = c & 63, g = c >> 6;
            size_t off = (size_t)row * lda + k0 + g*8;
            gl16(Ahi + off, Ah + (size_t)(c0 + ub)*8);
            gl16(Alo + off, Al + (size_t)(c0 + ub)*8);
        }
#pragma unroll
        for (int c0 = 0; c0 < BN*8; c0 += 256) {      // B: BN rows x 8 kgroups
            int c = c0 + tid;
            int row = c & (BN-1), g = c / BN;
            size_t off = (size_t)row * Kd + k0 + g*8;
            gl16(Whi + off, Bh + (size_t)(c0 + ub)*8);
            gl16(Wlo + off, Bl + (size_t)(c0 + ub)*8);
        }
        __syncthreads();
#pragma unroll
        for (int kk = 0; kk < 2; ++kk) {
            bf16x8 a_h[2], a_l[2], b_h[NJ], b_l[NJ];
#pragma unroll
            for (int i = 0; i < 2; ++i) {
                int ch = (kk*4 + kg)*64 + wr*32 + i*16 + r16;
                a_h[i] = __builtin_bit_cast(bf16x8, *(const u16x8*)(Ah + (size_t)ch*8));
                a_l[i] = __builtin_bit_cast(bf16x8, *(const u16x8*)(Al + (size_t)ch*8));
            }
#pragma unroll
            for (int j = 0; j < NJ; ++j) {
                int ch = (kk*4 + kg)*BN + wc*WN + j*16 + r16;
                b_h[j] = __builtin_bit_cast(bf16x8, *(const u16x8*)(Bh + (size_t)ch*8));
                b_l[j] = __builtin_bit_cast(bf16x8, *(const u16x8*)(Bl + (size_t)ch*8));
            }
#pragma unroll
            for (int i = 0; i < 2; ++i)
#pragma unroll
                for (int j = 0; j < NJ; ++j) {
                    acc[i][j] = __builtin_amdgcn_mfma_f32_16x16x32_bf16(a_h[i], b_h[j], acc[i][j], 0, 0, 0);
                    acc[i][j] = __builtin_amdgcn_mfma_f32_16x16x32_bf16(a_h[i], b_l[j], acc[i][j], 0, 0, 0);
                    acc[i][j] = __builtin_amdgcn_mfma_f32_16x16x32_bf16(a_l[i], b_h[j], acc[i][j], 0, 0, 0);
                }
        }
        __syncthreads();
    }
}

// persistent whole-SDE kernel. grid=512 blocks x 256 thr, all resident (48KB LDS -> 3/CU by LDS,
// launch_bounds(256,2) -> >=2/CU by VGPR; 512 = 256 CUs x 2).
// C/D frag: col = lane&15, row = (lane>>4)*4 + reg.
__global__ __launch_bounds__(256, 2) void sde_k(
    const float* __restrict__ ts,
    const float* __restrict__ dW,
    const float* __restrict__ g_w1, const float* __restrict__ g_b1,
    const float* __restrict__ f_w1, const float* __restrict__ f_b1,
    const float* __restrict__ f_b2, const float* __restrict__ f_b3,
    const float* __restrict__ g_b2,
    const unsigned short* __restrict__ w1tH, const unsigned short* __restrict__ w1tL,
    const unsigned short* __restrict__ gw2H, const unsigned short* __restrict__ gw2L,
    const unsigned short* __restrict__ fw2H, const unsigned short* __restrict__ fw2L,
    const unsigned short* __restrict__ fw3H, const unsigned short* __restrict__ fw3L,
    unsigned short* __restrict__ HAh, unsigned short* __restrict__ HAl,
    unsigned short* __restrict__ HBh, unsigned short* __restrict__ HBl,
    unsigned short* __restrict__ ytH, unsigned short* __restrict__ ytL,
    unsigned short* __restrict__ ycH, unsigned short* __restrict__ ycL,
    float* __restrict__ gp, float* __restrict__ drift,
    float* __restrict__ out,
    unsigned int* __restrict__ ctrs)
{
    __shared__ __align__(16) unsigned short lds[2*64*64 + 2*128*64];
    const int bid = blockIdx.x;
    const int tid = threadIdx.x, l = tid & 63, wid = tid >> 6;
    const int wr = wid >> 1, wc = wid & 1, r16 = l & 15, rg = l >> 4;
    const unsigned int tgt = gridDim.x;
    // XCD-friendly strip mapping for 512-tile phases
    const int q = bid >> 3;
    const int strip512 = (bid & 7)*2 + (q >> 5);   // 0..15
    const int rowb512  = q & 31;                   // 0..31

    for (int step = 0; step < NSTEP; ++step) {
        const float* y  = out + (size_t)step * B_ * S_;
        float*       y1 = out + (size_t)(step+1) * B_ * S_;
        const float* dWs = dW + (size_t)step * B_ * K_;
        const float tcur = ts[3+step];
        const float dt   = ts[4+step] - tcur;
        const float sq   = sqrtf(dt);

        // ---- P1: HA = relu([t,yc] @ [g_w1|f_w1]) (2048x1024), 512 tiles 64x64
        {
            const int rowBase = rowb512*64, colBase = strip512*64;
            f32x4 acc[2][2] = {};
            gemm_tile<64>(lds, ycH + (size_t)rowBase*S_, ycL + (size_t)rowBase*S_, S_,
                          w1tH + (size_t)colBase*128, w1tL + (size_t)colBase*128, 128, acc);
#pragma unroll
            for (int j = 0; j < 2; ++j) {
                int colj = colBase + wc*32 + j*16 + r16;
                float be = (colj < 512) ? (g_b1[colj] + tcur*g_w1[colj])
                                        : (f_b1[colj-512] + tcur*f_w1[colj-512]);
#pragma unroll
                for (int i = 0; i < 2; ++i)
#pragma unroll
                    for (int reg = 0; reg < 4; ++reg) {
                        int row = rowBase + wr*32 + i*16 + rg*4 + reg;
                        float v = fmaxf(acc[i][j][reg] + be, 0.f);
                        unsigned short h, lo; f2b2(v, h, lo);
                        size_t o = (size_t)row*1024 + colj;
                        HAh[o] = h; HAl[o] = lo;
                    }
            }
        }
        gbar(ctrs + step*4 + 0, tgt);

        // ---- P2: 512 g-tiles (64x128, K=512): gp + ytmp; 128 f-tiles: HB = relu(HA_f@f_w2+b)
        for (int t = bid; t < 640; t += GRID) {
            if (t < 512) {
                const int rowBase = rowb512*64, colBase = strip512*128;
                f32x4 acc[2][4] = {};
                gemm_tile<128>(lds, HAh + (size_t)rowBase*1024, HAl + (size_t)rowBase*1024, 1024,
                               gw2H + (size_t)colBase*H_, gw2L + (size_t)colBase*H_, H_, acc);
#pragma unroll
                for (int i = 0; i < 2; ++i)
#pragma unroll
                    for (int reg = 0; reg < 4; ++reg) {
                        int row = rowBase + wr*32 + i*16 + rg*4 + reg;
                        float dwv = dWs[row*K_ + r16] * sq;
#pragma unroll
                        for (int j = 0; j < 4; ++j) {
                            int colj = colBase + wc*64 + j*16;
                            float m = (acc[i][j][reg] + g_b2[colj + r16]) * dwv;
                            m += __shfl_xor(m,1); m += __shfl_xor(m,2);
                            m += __shfl_xor(m,4); m += __shfl_xor(m,8);
                            if (r16 == 0) {
                                int idx = row*S_ + (colj>>4);
                                gp[idx] = m;
                                unsigned short h, lo; f2b2(y[idx] + m, h, lo);
                                ytH[idx] = h; ytL[idx] = lo;
                            }
                        }
                    }
            } else {
                const int u = t - 512;                  // 0..127
                const int rowBase = (u & 31)*64, colBase = (u >> 5)*128;
                f32x4 acc[2][4] = {};
                gemm_tile<128>(lds, HAh + (size_t)rowBase*1024 + 512, HAl + (size_t)rowBase*1024 + 512, 1024,
                               fw2H + (size_t)colBase*H_, fw2L + (size_t)colBase*H_, H_, acc);
#pragma unroll
                for (int j = 0; j < 4; ++j) {
                    int colj = colBase + wc*64 + j*16 + r16;
                    float be = f_b2[colj];
#pragma unroll
                    for (int i = 0; i < 2; ++i)
#pragma unroll
                        for (int reg = 0; reg < 4; ++reg) {
                            int row = rowBase + wr*32 + i*16 + rg*4 + reg;
                            float v = fmaxf(acc[i][j][reg] + be, 0.f);
                            unsigned short h, lo; f2b2(v, h, lo);
                            size_t o = (size_t)row*512 + colj;
                            HBh[o] = h; HBl[o] = lo;
                        }
                }
            }
        }
        gbar(ctrs + step*4 + 1, tgt);

        // ---- P3: 256 tiles HA2 = relu([t,yt]@g_w1+b) (64x64); 64 tiles drift = HB@f_w3+b (64x64)
        if (bid < 320) {
            if (bid < 256) {
                const int rowBase = (bid & 31)*64, colBase = (bid >> 5)*64;
                f32x4 acc[2][2] = {};
                gemm_tile<64>(lds, ytH + (size_t)rowBase*S_, ytL + (size_t)rowBase*S_, S_,
                              w1tH + (size_t)colBase*128, w1tL + (size_t)colBase*128, 128, acc);
#pragma unroll
                for (int j = 0; j < 2; ++j) {
                    int colj = colBase + wc*32 + j*16 + r16;
                    float be = g_b1[colj] + tcur*g_w1[colj];
#pragma unroll
                    for (int i = 0; i < 2; ++i)
#pragma unroll
                        for (int reg = 0; reg < 4; ++reg) {
                            int row = rowBase + wr*32 + i*16 + rg*4 + reg;
                            float v = fmaxf(acc[i][j][reg] + be, 0.f);
                            unsigned short h, lo; f2b2(v, h, lo);
                            size_t o = (size_t)row*512 + colj;
                            // HA2 aliases HA (HA_g dead after P2) -- ld 512
                            HAh[o] = h; HAl[o] = lo;
                        }
                }
            } else {
                const int u = bid - 256;                // 0..63
                const int rowBase = (u & 31)*64, colBase = (u >> 5)*64;
                f32x4 acc[2][2] = {};
                gemm_tile<64>(lds, HBh + (size_t)rowBase*H_, HBl + (size_t)rowBase*H_, H_,
                              fw3H + (size_t)colBase*H_, fw3L + (size_t)colBase*H_, H_, acc);
#pragma unroll
                for (int j = 0; j < 2; ++j) {
                    int colj = colBase + wc*32 + j*16 + r16;
                    float be = f_b3[colj];
#pragma unroll
                    for (int i = 0; i < 2; ++i)
#pragma unroll
                        for (int reg = 0; reg < 4; ++reg) {
                            int row = rowBase + wr*32 + i*16 + rg*4 + reg;
                            drift[row*S_ + colj] = acc[i][j][reg] + be;
                        }
                }
            }
        }
        gbar(ctrs + step*4 + 2, tgt);

        // ---- P4: 512 g-tiles: gp2 + final update -> y1 (f32) + yc (hi/lo)
        {
            const int rowBase = rowb512*64, colBase = strip512*128;
            f32x4 acc[2][4] = {};
            gemm_tile<128>(lds, HAh + (size_t)rowBase*512, HAl + (size_t)rowBase*512, 512,
                           gw2H + (size_t)colBase*H_, gw2L + (size_t)colBase*H_, H_, acc);
#pragma unroll
            for (int i = 0; i < 2; ++i)
#pragma unroll
                for (int reg = 0; reg < 4; ++reg) {
                    int row = rowBase + wr*32 + i*16 + rg*4 + reg;
                    float dwv = dWs[row*K_ + r16] * sq;
#pragma unroll
                    for (int j = 0; j < 4; ++j) {
                        int colj = colBase + wc*64 + j*16;
                        float m = (acc[i][j][reg] + g_b2[colj + r16]) * dwv;
                        m += __shfl_xor(m,1); m += __shfl_xor(m,2);
                        m += __shfl_xor(m,4); m += __shfl_xor(m,8);
                        if (r16 == 0) {
                            int idx = row*S_ + (colj>>4);
                            float v1 = y[idx] + drift[idx]*dt + 0.5f*(gp[idx] + m);
                            y1[idx] = v1;
                            unsigned short h, lo; f2b2(v1, h, lo);
                            ycH[idx] = h; ycL[idx] = lo;
                        }
                    }
                }
        }
        gbar(ctrs + step*4 + 3, tgt);
    }
}

__global__ __launch_bounds__(256) void tcast_k(
    const float* __restrict__ in, int rowOff, int Kd, int N,
    unsigned short* __restrict__ outH, unsigned short* __restrict__ outL)
{
    __shared__ float tl[32][33];
    const int kb = blockIdx.x*32, nb = blockIdx.y*32;
    const int tx = threadIdx.x, ty = threadIdx.y;
    for (int r = ty; r < 32; r += 8)
        tl[r][tx] = in[(size_t)(rowOff + kb + r)*N + nb + tx];
    __syncthreads();
    for (int r = ty; r < 32; r += 8) {
        unsigned short h, lo; f2b2(tl[tx][r], h, lo);
        size_t o = (size_t)(nb + r)*Kd + kb + tx;
        outH[o] = h; outL[o] = lo;
    }
}

__global__ __launch_bounds__(128) void encoder_k(
    const float* __restrict__ x,
    const float* __restrict__ w1, const float* __restrict__ b1,
    const float* __restrict__ w2, const float* __restrict__ b2,
    float* __restrict__ y0,
    unsigned short* __restrict__ ycH, unsigned short* __restrict__ ycL)
{
    int b = blockIdx.x;
    __shared__ float h[H_];
    int tid = threadIdx.x;
    float x0 = x[b*3+0], x1 = x[b*3+1], x2 = x[b*3+2];
    for (int i = tid; i < H_; i += 128)
        h[i] = fmaxf(x0*w1[i] + x1*w1[H_+i] + x2*w1[2*H_+i] + b1[i], 0.f);
    __syncthreads();
    float acc = b2[tid];
    for (int k = 0; k < H_; ++k) acc += h[k]*w2[k*S_+tid];
    size_t o = (size_t)b*S_ + tid;
    y0[o] = acc;
    unsigned short hh, ll; f2b2(acc, hh, ll);
    ycH[o] = hh; ycL[o] = ll;
}

__global__ void zero_ctr_k(unsigned int* c) { c[threadIdx.x] = 0; }

extern "C" void kernel_launch(void* const* d_in, const int* in_sizes, int n_in,
                              void* d_out, int out_size, void* d_ws, size_t ws_size,
                              hipStream_t stream)
{
    const float* ts     = (const float*)d_in[0];
    const float* x      = (const float*)d_in[1];
    const float* enc_w1 = (const float*)d_in[2];
    const float* enc_b1 = (const float*)d_in[3];
    const float* enc_w2 = (const float*)d_in[4];
    const float* enc_b2 = (const float*)d_in[5];
    const float* f_w1   = (const float*)d_in[6];
    const float* f_b1   = (const float*)d_in[7];
    const float* f_w2   = (const float*)d_in[8];
    const float* f_b2   = (const float*)d_in[9];
    const float* f_w3   = (const float*)d_in[10];
    const float* f_b3   = (const float*)d_in[11];
    const float* g_w1   = (const float*)d_in[12];
    const float* g_b1   = (const float*)d_in[13];
    const float* g_w2   = (const float*)d_in[14];
    const float* g_b2   = (const float*)d_in[15];
    const float* dW     = (const float*)d_in[16];

    float* out = (float*)d_out;
    unsigned short* w = (unsigned short*)d_ws;

    unsigned short* w1tH  = w;                      // 1024*128
    unsigned short* w1tL  = w1tH  + 1024*128;
    unsigned short* gw2H  = w1tL  + 1024*128;       // 2048*512
    unsigned short* gw2L  = gw2H  + 2048*512;
    unsigned short* fw2H  = gw2L  + 2048*512;       // 512*512
    unsigned short* fw2L  = fw2H  + 512*512;
    unsigned short* fw3H  = fw2L  + 512*512;        // 128*512
    unsigned short* fw3L  = fw3H  + 128*512;
    unsigned short* HAh   = fw3L  + 128*512;        // 2048*1024
    unsigned short* HAl   = HAh   + 2048*1024;
    unsigned short* HBh   = HAl   + 2048*1024;      // 2048*512
    unsigned short* HBl   = HBh   + 2048*512;
    unsigned short* ytH   = HBl   + 2048*512;       // 2048*128
    unsigned short* ytL   = ytH   + 2048*128;
    unsigned short* ycH   = ytL   + 2048*128;       // 2048*128
    unsigned short* ycL   = ycH   + 2048*128;
    float* gp    = (float*)(ycL + 2048*128);        // 2048*128 f32
    float* drift = gp + 2048*128;                   // 2048*128 f32
    unsigned int* ctrs = (unsigned int*)(drift + 2048*128);  // 256 uints

    dim3 tb(32,8);
    tcast_k<<<dim3(4,16),  tb, 0, stream>>>(g_w1, 1, 128, 512,  w1tH,          w1tL);
    tcast_k<<<dim3(4,16),  tb, 0, stream>>>(f_w1, 1, 128, 512,  w1tH+512*128,  w1tL+512*128);
    tcast_k<<<dim3(16,16), tb, 0, stream>>>(f_w2, 0, 512, 512,  fw2H,          fw2L);
    tcast_k<<<dim3(16,4),  tb, 0, stream>>>(f_w3, 0, 512, 128,  fw3H,          fw3L);
    tcast_k<<<dim3(16,64), tb, 0, stream>>>(g_w2, 0, 512, 2048, gw2H,          gw2L);

    encoder_k<<<B_, 128, 0, stream>>>(x, enc_w1, enc_b1, enc_w2, enc_b2, out, ycH, ycL);
    zero_ctr_k<<<1, 256, 0, stream>>>(ctrs);

    sde_k<<<GRID, 256, 0, stream>>>(
        ts, dW, g_w1, g_b1, f_w1, f_b1, f_b2, f_b3, g_b2,
        w1tH, w1tL, gw2H, gw2L, fw2H, fw2L, fw3H, fw3L,
        HAh, HAl, HBh, HBl, ytH, ytL, ycH, ycL,
        gp, drift, out, ctrs);
}

// Round 7
// 29085.336 us; speedup vs baseline: 1.6005x; 1.0088x over previous
//
#include <hip/hip_runtime.h>
#include <hip/hip_bf16.h>
#include <math.h>

#define B_  2048
#define S_  128
#define H_  512
#define K_  16
#define NSTEP 63
#define GRID 512

typedef __bf16 bf16x8 __attribute__((ext_vector_type(8)));
typedef float  f32x4  __attribute__((ext_vector_type(4)));
typedef unsigned short u16x8 __attribute__((ext_vector_type(8)));

static __device__ __forceinline__ void f2b2(float v, unsigned short& hi, unsigned short& lo)
{
    __hip_bfloat16 h = __float2bfloat16(v);
    float r = v - __bfloat162float(h);
    __hip_bfloat16 l = __float2bfloat16(r);
    hi = __builtin_bit_cast(unsigned short, h);
    lo = __builtin_bit_cast(unsigned short, l);
}

static __device__ __forceinline__ void gl16(const unsigned short* g, unsigned short* l)
{
    __builtin_amdgcn_global_load_lds(
        (const __attribute__((address_space(1))) unsigned int*)g,
        (__attribute__((address_space(3))) unsigned int*)l, 16, 0, 0);
}

// device-scope grid barrier.
//  - arrival: RELEASE fetch_add (one L2 writeback; makes this block's phase writes visible)
//  - poll: RELAXED atomic RMW (+0) -- RMWs execute at the coherence point, so remote
//    arrivals are observed directly (a relaxed LOAD would spin on a stale local-L2 line);
//    s_sleep(1) backoff keeps 512 pollers from saturating the TCC atomic slot
//  - exit: one ACQUIRE load (single cache invalidate; we see remote phase writes)
//  - hedge: ACQUIRE poll every 128 spins (liveness safety)
static __device__ __forceinline__ void gbar(unsigned int* c, unsigned int target)
{
    __syncthreads();
    if (threadIdx.x == 0) {
        __hip_atomic_fetch_add(c, 1u, __ATOMIC_RELEASE, __HIP_MEMORY_SCOPE_AGENT);
        int spins = 0;
        while (true) {
            unsigned int v = ((++spins & 127) == 0)
                ? __hip_atomic_load(c, __ATOMIC_ACQUIRE, __HIP_MEMORY_SCOPE_AGENT)
                : __hip_atomic_fetch_add(c, 0u, __ATOMIC_RELAXED, __HIP_MEMORY_SCOPE_AGENT);
            if (v >= target) break;
            __builtin_amdgcn_s_sleep(1);
        }
        (void)__hip_atomic_load(c, __ATOMIC_ACQUIRE, __HIP_MEMORY_SCOPE_AGENT);
    }
    __syncthreads();
}

// ---- GEMM tile: BM=64, BK=64, BN in {64,128}; 4 waves 2x2 (WM=32, WN=BN/2).
// A pre-offset by rowBase*lda; W pre-transposed [N][K] pre-offset by colBase*K.
// LDS planes [Ah|Al|Bh|Bl]; 16B chunks linear in load order.
// 3-MFMA split: ah*bh + ah*bl + al*bh, f32 accum.
template<int BN>
static __device__ __forceinline__ void gemm_tile(
    unsigned short* lds,
    const unsigned short* __restrict__ Ahi, const unsigned short* __restrict__ Alo, int lda,
    const unsigned short* __restrict__ Whi, const unsigned short* __restrict__ Wlo, int Kd,
    f32x4 (&acc)[2][BN/32])
{
    constexpr int NJ = BN/32, WN = BN/2;
    constexpr int PLA = 64*64, PLB = BN*64;
    unsigned short* Ah = lds;
    unsigned short* Al = lds + PLA;
    unsigned short* Bh = lds + 2*PLA;
    unsigned short* Bl = lds + 2*PLA + PLB;

    const int tid = threadIdx.x, lane = tid & 63;
    const int wid = tid >> 6, wr = wid >> 1, wc = wid & 1;
    const int r16 = lane & 15, kg = lane >> 4;
    const int ub = tid & ~63;

    for (int k0 = 0; k0 < Kd; k0 += 64) {
#pragma unroll
        for (int c0 = 0; c0 < 512; c0 += 256) {       // A: 64 rows x 8 kgroups
            int c = c0 + tid;
            int row = c & 63, g = c >> 6;
            size_t off = (size_t)row * lda + k0 + g*8;
            gl16(Ahi + off, Ah + (size_t)(c0 + ub)*8);
            gl16(Alo + off, Al + (size_t)(c0 + ub)*8);
        }
#pragma unroll
        for (int c0 = 0; c0 < BN*8; c0 += 256) {      // B: BN rows x 8 kgroups
            int c = c0 + tid;
            int row = c & (BN-1), g = c / BN;
            size_t off = (size_t)row * Kd + k0 + g*8;
            gl16(Whi + off, Bh + (size_t)(c0 + ub)*8);
            gl16(Wlo + off, Bl + (size_t)(c0 + ub)*8);
        }
        __syncthreads();
#pragma unroll
        for (int kk = 0; kk < 2; ++kk) {
            bf16x8 a_h[2], a_l[2], b_h[NJ], b_l[NJ];
#pragma unroll
            for (int i = 0; i < 2; ++i) {
                int ch = (kk*4 + kg)*64 + wr*32 + i*16 + r16;
                a_h[i] = __builtin_bit_cast(bf16x8, *(const u16x8*)(Ah + (size_t)ch*8));
                a_l[i] = __builtin_bit_cast(bf16x8, *(const u16x8*)(Al + (size_t)ch*8));
            }
#pragma unroll
            for (int j = 0; j < NJ; ++j) {
                int ch = (kk*4 + kg)*BN + wc*WN + j*16 + r16;
                b_h[j] = __builtin_bit_cast(bf16x8, *(const u16x8*)(Bh + (size_t)ch*8));
                b_l[j] = __builtin_bit_cast(bf16x8, *(const u16x8*)(Bl + (size_t)ch*8));
            }
#pragma unroll
            for (int i = 0; i < 2; ++i)
#pragma unroll
                for (int j = 0; j < NJ; ++j) {
                    acc[i][j] = __builtin_amdgcn_mfma_f32_16x16x32_bf16(a_h[i], b_h[j], acc[i][j], 0, 0, 0);
                    acc[i][j] = __builtin_amdgcn_mfma_f32_16x16x32_bf16(a_h[i], b_l[j], acc[i][j], 0, 0, 0);
                    acc[i][j] = __builtin_amdgcn_mfma_f32_16x16x32_bf16(a_l[i], b_h[j], acc[i][j], 0, 0, 0);
                }
        }
        __syncthreads();
    }
}

// persistent whole-SDE kernel. grid=512 blocks x 256 thr, all resident.
// C/D frag: col = lane&15, row = (lane>>4)*4 + reg.
__global__ __launch_bounds__(256, 2) void sde_k(
    const float* __restrict__ ts,
    const float* __restrict__ dW,
    const float* __restrict__ g_w1, const float* __restrict__ g_b1,
    const float* __restrict__ f_w1, const float* __restrict__ f_b1,
    const float* __restrict__ f_b2, const float* __restrict__ f_b3,
    const float* __restrict__ g_b2,
    const unsigned short* __restrict__ w1tH, const unsigned short* __restrict__ w1tL,
    const unsigned short* __restrict__ gw2H, const unsigned short* __restrict__ gw2L,
    const unsigned short* __restrict__ fw2H, const unsigned short* __restrict__ fw2L,
    const unsigned short* __restrict__ fw3H, const unsigned short* __restrict__ fw3L,
    unsigned short* __restrict__ HAh, unsigned short* __restrict__ HAl,
    unsigned short* __restrict__ HBh, unsigned short* __restrict__ HBl,
    unsigned short* __restrict__ ytH, unsigned short* __restrict__ ytL,
    unsigned short* __restrict__ ycH, unsigned short* __restrict__ ycL,
    float* __restrict__ gp, float* __restrict__ drift,
    float* __restrict__ out,
    unsigned int* __restrict__ ctrs)
{
    __shared__ __align__(16) unsigned short lds[2*64*64 + 2*128*64];
    const int bid = blockIdx.x;
    const int tid = threadIdx.x, l = tid & 63, wid = tid >> 6;
    const int wr = wid >> 1, wc = wid & 1, r16 = l & 15, rg = l >> 4;
    const unsigned int tgt = gridDim.x;
    // XCD-friendly strip mapping for 512-tile phases
    const int q = bid >> 3;
    const int strip512 = (bid & 7)*2 + (q >> 5);   // 0..15
    const int rowb512  = q & 31;                   // 0..31

    for (int step = 0; step < NSTEP; ++step) {
        const float* y  = out + (size_t)step * B_ * S_;
        float*       y1 = out + (size_t)(step+1) * B_ * S_;
        const float* dWs = dW + (size_t)step * B_ * K_;
        const float tcur = ts[3+step];
        const float dt   = ts[4+step] - tcur;
        const float sq   = sqrtf(dt);

        // ---- P1: HA = relu([t,yc] @ [g_w1|f_w1]) (2048x1024), 512 tiles 64x64
        {
            const int rowBase = rowb512*64, colBase = strip512*64;
            f32x4 acc[2][2] = {};
            gemm_tile<64>(lds, ycH + (size_t)rowBase*S_, ycL + (size_t)rowBase*S_, S_,
                          w1tH + (size_t)colBase*128, w1tL + (size_t)colBase*128, 128, acc);
#pragma unroll
            for (int j = 0; j < 2; ++j) {
                int colj = colBase + wc*32 + j*16 + r16;
                float be = (colj < 512) ? (g_b1[colj] + tcur*g_w1[colj])
                                        : (f_b1[colj-512] + tcur*f_w1[colj-512]);
#pragma unroll
                for (int i = 0; i < 2; ++i)
#pragma unroll
                    for (int reg = 0; reg < 4; ++reg) {
                        int row = rowBase + wr*32 + i*16 + rg*4 + reg;
                        float v = fmaxf(acc[i][j][reg] + be, 0.f);
                        unsigned short h, lo; f2b2(v, h, lo);
                        size_t o = (size_t)row*1024 + colj;
                        HAh[o] = h; HAl[o] = lo;
                    }
            }
        }
        gbar(ctrs + step*4 + 0, tgt);

        // ---- P2: 512 g-tiles (64x128, K=512): gp + ytmp; 128 f-tiles: HB = relu(HA_f@f_w2+b)
        for (int t = bid; t < 640; t += GRID) {
            if (t < 512) {
                const int rowBase = rowb512*64, colBase = strip512*128;
                f32x4 acc[2][4] = {};
                gemm_tile<128>(lds, HAh + (size_t)rowBase*1024, HAl + (size_t)rowBase*1024, 1024,
                               gw2H + (size_t)colBase*H_, gw2L + (size_t)colBase*H_, H_, acc);
#pragma unroll
                for (int i = 0; i < 2; ++i)
#pragma unroll
                    for (int reg = 0; reg < 4; ++reg) {
                        int row = rowBase + wr*32 + i*16 + rg*4 + reg;
                        float dwv = dWs[row*K_ + r16] * sq;
#pragma unroll
                        for (int j = 0; j < 4; ++j) {
                            int colj = colBase + wc*64 + j*16;
                            float m = (acc[i][j][reg] + g_b2[colj + r16]) * dwv;
                            m += __shfl_xor(m,1); m += __shfl_xor(m,2);
                            m += __shfl_xor(m,4); m += __shfl_xor(m,8);
                            if (r16 == 0) {
                                int idx = row*S_ + (colj>>4);
                                gp[idx] = m;
                                unsigned short h, lo; f2b2(y[idx] + m, h, lo);
                                ytH[idx] = h; ytL[idx] = lo;
                            }
                        }
                    }
            } else {
                const int u = t - 512;                  // 0..127
                const int rowBase = (u & 31)*64, colBase = (u >> 5)*128;
                f32x4 acc[2][4] = {};
                gemm_tile<128>(lds, HAh + (size_t)rowBase*1024 + 512, HAl + (size_t)rowBase*1024 + 512, 1024,
                               fw2H + (size_t)colBase*H_, fw2L + (size_t)colBase*H_, H_, acc);
#pragma unroll
                for (int j = 0; j < 4; ++j) {
                    int colj = colBase + wc*64 + j*16 + r16;
                    float be = f_b2[colj];
#pragma unroll
                    for (int i = 0; i < 2; ++i)
#pragma unroll
                        for (int reg = 0; reg < 4; ++reg) {
                            int row = rowBase + wr*32 + i*16 + rg*4 + reg;
                            float v = fmaxf(acc[i][j][reg] + be, 0.f);
                            unsigned short h, lo; f2b2(v, h, lo);
                            size_t o = (size_t)row*512 + colj;
                            HBh[o] = h; HBl[o] = lo;
                        }
                }
            }
        }
        gbar(ctrs + step*4 + 1, tgt);

        // ---- P3: 256 tiles HA2 = relu([t,yt]@g_w1+b) (64x64); 64 tiles drift = HB@f_w3+b (64x64)
        if (bid < 320) {
            if (bid < 256) {
                const int rowBase = (bid & 31)*64, colBase = (bid >> 5)*64;
                f32x4 acc[2][2] = {};
                gemm_tile<64>(lds, ytH + (size_t)rowBase*S_, ytL + (size_t)rowBase*S_, S_,
                              w1tH + (size_t)colBase*128, w1tL + (size_t)colBase*128, 128, acc);
#pragma unroll
                for (int j = 0; j < 2; ++j) {
                    int colj = colBase + wc*32 + j*16 + r16;
                    float be = g_b1[colj] + tcur*g_w1[colj];
#pragma unroll
                    for (int i = 0; i < 2; ++i)
#pragma unroll
                        for (int reg = 0; reg < 4; ++reg) {
                            int row = rowBase + wr*32 + i*16 + rg*4 + reg;
                            float v = fmaxf(acc[i][j][reg] + be, 0.f);
                            unsigned short h, lo; f2b2(v, h, lo);
                            size_t o = (size_t)row*512 + colj;
                            // HA2 aliases HA (HA_g dead after P2) -- ld 512
                            HAh[o] = h; HAl[o] = lo;
                        }
                }
            } else {
                const int u = bid - 256;                // 0..63
                const int rowBase = (u & 31)*64, colBase = (u >> 5)*64;
                f32x4 acc[2][2] = {};
                gemm_tile<64>(lds, HBh + (size_t)rowBase*H_, HBl + (size_t)rowBase*H_, H_,
                              fw3H + (size_t)colBase*H_, fw3L + (size_t)colBase*H_, H_, acc);
#pragma unroll
                for (int j = 0; j < 2; ++j) {
                    int colj = colBase + wc*32 + j*16 + r16;
                    float be = f_b3[colj];
#pragma unroll
                    for (int i = 0; i < 2; ++i)
#pragma unroll
                        for (int reg = 0; reg < 4; ++reg) {
                            int row = rowBase + wr*32 + i*16 + rg*4 + reg;
                            drift[row*S_ + colj] = acc[i][j][reg] + be;
                        }
                }
            }
        }
        gbar(ctrs + step*4 + 2, tgt);

        // ---- P4: 512 g-tiles: gp2 + final update -> y1 (f32) + yc (hi/lo)
        {
            const int rowBase = rowb512*64, colBase = strip512*128;
            f32x4 acc[2][4] = {};
            gemm_tile<128>(lds, HAh + (size_t)rowBase*512, HAl + (size_t)rowBase*512, 512,
                           gw2H + (size_t)colBase*H_, gw2L + (size_t)colBase*H_, H_, acc);
#pragma unroll
            for (int i = 0; i < 2; ++i)
#pragma unroll
                for (int reg = 0; reg < 4; ++reg) {
                    int row = rowBase + wr*32 + i*16 + rg*4 + reg;
                    float dwv = dWs[row*K_ + r16] * sq;
#pragma unroll
                    for (int j = 0; j < 4; ++j) {
                        int colj = colBase + wc*64 + j*16;
                        float m = (acc[i][j][reg] + g_b2[colj + r16]) * dwv;
                        m += __shfl_xor(m,1); m += __shfl_xor(m,2);
                        m += __shfl_xor(m,4); m += __shfl_xor(m,8);
                        if (r16 == 0) {
                            int idx = row*S_ + (colj>>4);
                            float v1 = y[idx] + drift[idx]*dt + 0.5f*(gp[idx] + m);
                            y1[idx] = v1;
                            unsigned short h, lo; f2b2(v1, h, lo);
                            ycH[idx] = h; ycL[idx] = lo;
                        }
                    }
                }
        }
        gbar(ctrs + step*4 + 3, tgt);
    }
}

__global__ __launch_bounds__(256) void tcast_k(
    const float* __restrict__ in, int rowOff, int Kd, int N,
    unsigned short* __restrict__ outH, unsigned short* __restrict__ outL)
{
    __shared__ float tl[32][33];
    const int kb = blockIdx.x*32, nb = blockIdx.y*32;
    const int tx = threadIdx.x, ty = threadIdx.y;
    for (int r = ty; r < 32; r += 8)
        tl[r][tx] = in[(size_t)(rowOff + kb + r)*N + nb + tx];
    __syncthreads();
    for (int r = ty; r < 32; r += 8) {
        unsigned short h, lo; f2b2(tl[tx][r], h, lo);
        size_t o = (size_t)(nb + r)*Kd + kb + tx;
        outH[o] = h; outL[o] = lo;
    }
}

__global__ __launch_bounds__(128) void encoder_k(
    const float* __restrict__ x,
    const float* __restrict__ w1, const float* __restrict__ b1,
    const float* __restrict__ w2, const float* __restrict__ b2,
    float* __restrict__ y0,
    unsigned short* __restrict__ ycH, unsigned short* __restrict__ ycL)
{
    int b = blockIdx.x;
    __shared__ float h[H_];
    int tid = threadIdx.x;
    float x0 = x[b*3+0], x1 = x[b*3+1], x2 = x[b*3+2];
    for (int i = tid; i < H_; i += 128)
        h[i] = fmaxf(x0*w1[i] + x1*w1[H_+i] + x2*w1[2*H_+i] + b1[i], 0.f);
    __syncthreads();
    float acc = b2[tid];
    for (int k = 0; k < H_; ++k) acc += h[k]*w2[k*S_+tid];
    size_t o = (size_t)b*S_ + tid;
    y0[o] = acc;
    unsigned short hh, ll; f2b2(acc, hh, ll);
    ycH[o] = hh; ycL[o] = ll;
}

__global__ void zero_ctr_k(unsigned int* c) { c[threadIdx.x] = 0; }

extern "C" void kernel_launch(void* const* d_in, const int* in_sizes, int n_in,
                              void* d_out, int out_size, void* d_ws, size_t ws_size,
                              hipStream_t stream)
{
    const float* ts     = (const float*)d_in[0];
    const float* x      = (const float*)d_in[1];
    const float* enc_w1 = (const float*)d_in[2];
    const float* enc_b1 = (const float*)d_in[3];
    const float* enc_w2 = (const float*)d_in[4];
    const float* enc_b2 = (const float*)d_in[5];
    const float* f_w1   = (const float*)d_in[6];
    const float* f_b1   = (const float*)d_in[7];
    const float* f_w2   = (const float*)d_in[8];
    const float* f_b2   = (const float*)d_in[9];
    const float* f_w3   = (const float*)d_in[10];
    const float* f_b3   = (const float*)d_in[11];
    const float* g_w1   = (const float*)d_in[12];
    const float* g_b1   = (const float*)d_in[13];
    const float* g_w2   = (const float*)d_in[14];
    const float* g_b2   = (const float*)d_in[15];
    const float* dW     = (const float*)d_in[16];

    float* out = (float*)d_out;
    unsigned short* w = (unsigned short*)d_ws;

    unsigned short* w1tH  = w;                      // 1024*128
    unsigned short* w1tL  = w1tH  + 1024*128;
    unsigned short* gw2H  = w1tL  + 1024*128;       // 2048*512
    unsigned short* gw2L  = gw2H  + 2048*512;
    unsigned short* fw2H  = gw2L  + 2048*512;       // 512*512
    unsigned short* fw2L  = fw2H  + 512*512;
    unsigned short* fw3H  = fw2L  + 512*512;        // 128*512
    unsigned short* fw3L  = fw3H  + 128*512;
    unsigned short* HAh   = fw3L  + 128*512;        // 2048*1024
    unsigned short* HAl   = HAh   + 2048*1024;
    unsigned short* HBh   = HAl   + 2048*1024;      // 2048*512
    unsigned short* HBl   = HBh   + 2048*512;
    unsigned short* ytH   = HBl   + 2048*512;       // 2048*128
    unsigned short* ytL   = ytH   + 2048*128;
    unsigned short* ycH   = ytL   + 2048*128;       // 2048*128
    unsigned short* ycL   = ycH   + 2048*128;
    float* gp    = (float*)(ycL + 2048*128);        // 2048*128 f32
    float* drift = gp + 2048*128;                   // 2048*128 f32
    unsigned int* ctrs = (unsigned int*)(drift + 2048*128);  // 256 uints

    dim3 tb(32,8);
    tcast_k<<<dim3(4,16),  tb, 0, stream>>>(g_w1, 1, 128, 512,  w1tH,          w1tL);
    tcast_k<<<dim3(4,16),  tb, 0, stream>>>(f_w1, 1, 128, 512,  w1tH+512*128,  w1tL+512*128);
    tcast_k<<<dim3(16,16), tb, 0, stream>>>(f_w2, 0, 512, 512,  fw2H,          fw2L);
    tcast_k<<<dim3(16,4),  tb, 0, stream>>>(f_w3, 0, 512, 128,  fw3H,          fw3L);
    tcast_k<<<dim3(16,64), tb, 0, stream>>>(g_w2, 0, 512, 2048, gw2H,          gw2L);

    encoder_k<<<B_, 128, 0, stream>>>(x, enc_w1, enc_b1, enc_w2, enc_b2, out, ycH, ycL);
    zero_ctr_k<<<1, 256, 0, stream>>>(ctrs);

    sde_k<<<GRID, 256, 0, stream>>>(
        ts, dW, g_w1, g_b1, f_w1, f_b1, f_b2, f_b3, g_b2,
        w1tH, w1tL, gw2H, gw2L, fw2H, fw2L, fw3H, fw3L,
        HAh, HAl, HBh, HBl, ytH, ytL, ycH, ycL,
        gp, drift, out, ctrs);
}

// Round 8
// 19080.231 us; speedup vs baseline: 2.4398x; 1.5244x over previous
//
#include <hip/hip_runtime.h>
#include <hip/hip_bf16.h>
#include <math.h>

#define B_  2048
#define S_  128
#define H_  512
#define NSTEP 63
#define NBLK 128
#define R_   16      // rows per block
#define THREADS 1024 // 16 waves

typedef __bf16 bf16x8 __attribute__((ext_vector_type(8)));
typedef float  f32x4  __attribute__((ext_vector_type(4)));
typedef unsigned short u16x8 __attribute__((ext_vector_type(8)));

static __device__ __forceinline__ void f2b2(float v, unsigned short& hi, unsigned short& lo)
{
    __hip_bfloat16 h = __float2bfloat16(v);
    float r = v - __bfloat162float(h);
    __hip_bfloat16 l = __float2bfloat16(r);
    hi = __builtin_bit_cast(unsigned short, h);
    lo = __builtin_bit_cast(unsigned short, l);
}

static __device__ __forceinline__ bf16x8 frag_ld(const unsigned short* p)
{
    return __builtin_bit_cast(bf16x8, *(const u16x8*)p);
}

// Per-wave GEMM: A (16 x Kd) from LDS [row][k] (stride lda, 2-way-bank-free pads),
// B streamed from global W^T [n][Kb] hi/lo planes, G output frags at nBase.
// 3-MFMA split: ah*bh + ah*bl + al*bh, f32 accum.
// A-frag: row = lane&15, k = (lane>>4)*8 ; B-frag: n-row = nBase+j*16+(lane&15).
template<int G>
static __device__ __forceinline__ void wgemm(
    const unsigned short* __restrict__ Ah, const unsigned short* __restrict__ Al, int lda, int Kd,
    const unsigned short* __restrict__ Bh, const unsigned short* __restrict__ Bl, int Kb,
    int nBase, int lane, f32x4 (&acc)[G])
{
    const int r16 = lane & 15, kg = lane >> 4;
    const unsigned short* ah = Ah + r16*lda + kg*8;
    const unsigned short* al = Al + r16*lda + kg*8;
    size_t bo[G];
#pragma unroll
    for (int j = 0; j < G; ++j) bo[j] = (size_t)(nBase + j*16 + r16)*Kb + kg*8;
#pragma unroll 2
    for (int k = 0; k < Kd; k += 32) {
        bf16x8 a_h = frag_ld(ah + k);
        bf16x8 a_l = frag_ld(al + k);
#pragma unroll
        for (int j = 0; j < G; ++j) {
            bf16x8 b_h = __builtin_bit_cast(bf16x8, *(const u16x8*)(Bh + bo[j] + k));
            bf16x8 b_l = __builtin_bit_cast(bf16x8, *(const u16x8*)(Bl + bo[j] + k));
            acc[j] = __builtin_amdgcn_mfma_f32_16x16x32_bf16(a_h, b_h, acc[j], 0, 0, 0);
            acc[j] = __builtin_amdgcn_mfma_f32_16x16x32_bf16(a_h, b_l, acc[j], 0, 0, 0);
            acc[j] = __builtin_amdgcn_mfma_f32_16x16x32_bf16(a_l, b_h, acc[j], 0, 0, 0);
        }
    }
}

// Persistent row-slab kernel: block owns 16 batch rows for ALL 63 steps.
// All activations in LDS; weights streamed (read-only, shared via L2).
// NO grid barriers / fences needed for correctness (no cross-block data flow).
// C/D frag: col = lane&15, row = (lane>>4)*4 + reg.
__global__ __launch_bounds__(THREADS, 4) void sde_k(
    const float* __restrict__ ts, const float* __restrict__ dW,
    const float* __restrict__ g_w1, const float* __restrict__ g_b1,
    const float* __restrict__ f_w1, const float* __restrict__ f_b1,
    const float* __restrict__ f_b2, const float* __restrict__ f_b3,
    const float* __restrict__ g_b2,
    const unsigned short* __restrict__ w1tH, const unsigned short* __restrict__ w1tL,
    const unsigned short* __restrict__ gw2H, const unsigned short* __restrict__ gw2L,
    const unsigned short* __restrict__ fw2H, const unsigned short* __restrict__ fw2L,
    const unsigned short* __restrict__ fw3H, const unsigned short* __restrict__ fw3L,
    float* __restrict__ out, unsigned int* __restrict__ ctrs)
{
    // strides padded to 16B multiples with 2-way-max bank aliasing (free)
    __shared__ __align__(16) unsigned short HAh[R_*1032], HAl[R_*1032]; // 16x1024 (g|f), pad 8
    __shared__ __align__(16) unsigned short HBh[R_*520],  HBl[R_*520];  // 16x512, pad 8
    __shared__ __align__(16) unsigned short ycH[R_*136],  ycL[R_*136];  // 16x128, pad 8
    __shared__ __align__(16) unsigned short ytH[R_*136],  ytL[R_*136];
    __shared__ float y_s[R_*128], gp_s[R_*128], dr_s[R_*128];

    const int bid = blockIdx.x, tid = threadIdx.x;
    const int w = tid >> 6, lane = tid & 63;
    const int r16 = lane & 15, kg = lane >> 4;
    const int r0 = bid * R_;

    // prologue: y0 (from encoder, in out slice 0) -> y_s + yc hi/lo
    for (int i = tid; i < R_*128; i += THREADS) {
        int row = i >> 7, col = i & 127;
        float v = out[(size_t)(r0 + row)*S_ + col];
        y_s[i] = v;
        unsigned short h, lo; f2b2(v, h, lo);
        ycH[row*136 + col] = h; ycL[row*136 + col] = lo;
    }
    __syncthreads();

    for (int step = 0; step < NSTEP; ++step) {
        const float tcur = ts[3+step];
        const float dt   = ts[4+step] - tcur;
        const float sq   = sqrtf(dt);
        const float* dWs = dW + (size_t)step * B_ * 16;
        float dwv[4];
#pragma unroll
        for (int reg = 0; reg < 4; ++reg)
            dwv[reg] = dWs[(r0 + kg*4 + reg)*16 + r16] * sq;

        // ---- P1: HA = relu([t,yc] @ [g_w1|f_w1]) ; N=1024, 4 frags/wave
        {
            f32x4 acc[4] = {};
            wgemm<4>(ycH, ycL, 136, 128, w1tH, w1tL, 128, w*64, lane, acc);
#pragma unroll
            for (int j = 0; j < 4; ++j) {
                int col = w*64 + j*16 + r16;
                float be = (col < 512) ? (g_b1[col] + tcur*g_w1[col])
                                       : (f_b1[col-512] + tcur*f_w1[col-512]);
#pragma unroll
                for (int reg = 0; reg < 4; ++reg) {
                    int row = kg*4 + reg;
                    float v = fmaxf(acc[j][reg] + be, 0.f);
                    unsigned short h, lo; f2b2(v, h, lo);
                    HAh[row*1032 + col] = h; HAl[row*1032 + col] = lo;
                }
            }
        }
        __syncthreads();

        // ---- P2g: gp = contract(HA_g @ g_w2 + b, dW*sq) ; yt = y + gp ; 8 frags (2 groups)
        for (int grp = 0; grp < 2; ++grp) {
            f32x4 acc[4] = {};
            int nb = w*128 + grp*64;
            wgemm<4>(HAh, HAl, 1032, 512, gw2H, gw2L, 512, nb, lane, acc);
#pragma unroll
            for (int j = 0; j < 4; ++j) {
                int s = w*8 + grp*4 + j;
                float bb = g_b2[nb + j*16 + r16];
#pragma unroll
                for (int reg = 0; reg < 4; ++reg) {
                    float m = (acc[j][reg] + bb) * dwv[reg];
                    m += __shfl_xor(m,1); m += __shfl_xor(m,2);
                    m += __shfl_xor(m,4); m += __shfl_xor(m,8);
                    if (r16 == 0) {
                        int row = kg*4 + reg;
                        gp_s[row*128 + s] = m;
                        float yv = y_s[row*128 + s] + m;
                        unsigned short h, lo; f2b2(yv, h, lo);
                        ytH[row*136 + s] = h; ytL[row*136 + s] = lo;
                    }
                }
            }
        }
        // ---- P2f: HB = relu(HA_f @ f_w2 + b) ; 2 frags
        {
            f32x4 acc[2] = {};
            wgemm<2>(HAh + 512, HAl + 512, 1032, 512, fw2H, fw2L, 512, w*32, lane, acc);
#pragma unroll
            for (int j = 0; j < 2; ++j) {
                int col = w*32 + j*16 + r16;
                float be = f_b2[col];
#pragma unroll
                for (int reg = 0; reg < 4; ++reg) {
                    int row = kg*4 + reg;
                    float v = fmaxf(acc[j][reg] + be, 0.f);
                    unsigned short h, lo; f2b2(v, h, lo);
                    HBh[row*520 + col] = h; HBl[row*520 + col] = lo;
                }
            }
        }
        __syncthreads();

        // ---- P3a: HA2 = relu([t,yt] @ g_w1 + b) -> overwrite HA cols 0..511 ; 2 frags
        {
            f32x4 acc[2] = {};
            wgemm<2>(ytH, ytL, 136, 128, w1tH, w1tL, 128, w*32, lane, acc);
#pragma unroll
            for (int j = 0; j < 2; ++j) {
                int col = w*32 + j*16 + r16;           // 0..511
                float be = g_b1[col] + tcur*g_w1[col];
#pragma unroll
                for (int reg = 0; reg < 4; ++reg) {
                    int row = kg*4 + reg;
                    float v = fmaxf(acc[j][reg] + be, 0.f);
                    unsigned short h, lo; f2b2(v, h, lo);
                    HAh[row*1032 + col] = h; HAl[row*1032 + col] = lo;
                }
            }
        }
        // ---- P3b: drift = HB @ f_w3 + b ; waves 0..7, 1 frag
        if (w < 8) {
            f32x4 acc1[1] = {};
            wgemm<1>(HBh, HBl, 520, 512, fw3H, fw3L, 512, w*16, lane, acc1);
            int col = w*16 + r16;
            float be = f_b3[col];
#pragma unroll
            for (int reg = 0; reg < 4; ++reg)
                dr_s[(kg*4 + reg)*128 + col] = acc1[0][reg] + be;
        }
        __syncthreads();

        // ---- P4: gp2 + final update -> y1 (global out), y_s, yc
        float* y1 = out + (size_t)(step+1) * B_ * S_;
        for (int grp = 0; grp < 2; ++grp) {
            f32x4 acc[4] = {};
            int nb = w*128 + grp*64;
            wgemm<4>(HAh, HAl, 1032, 512, gw2H, gw2L, 512, nb, lane, acc);
#pragma unroll
            for (int j = 0; j < 4; ++j) {
                int s = w*8 + grp*4 + j;
                float bb = g_b2[nb + j*16 + r16];
#pragma unroll
                for (int reg = 0; reg < 4; ++reg) {
                    float m = (acc[j][reg] + bb) * dwv[reg];
                    m += __shfl_xor(m,1); m += __shfl_xor(m,2);
                    m += __shfl_xor(m,4); m += __shfl_xor(m,8);
                    if (r16 == 0) {
                        int row = kg*4 + reg;
                        int idx = row*128 + s;
                        float v1 = y_s[idx] + dr_s[idx]*dt + 0.5f*(gp_s[idx] + m);
                        y1[(size_t)(r0 + row)*S_ + s] = v1;
                        y_s[idx] = v1;
                        unsigned short h, lo; f2b2(v1, h, lo);
                        ycH[row*136 + s] = h; ycL[row*136 + s] = lo;
                    }
                }
            }
        }

        // ---- soft pacing barrier: keeps same-XCD blocks streaming weights in lockstep.
        // Relaxed atomics only, NO fences (no data crosses blocks -> perf-only, correctness-safe).
        __syncthreads();
        if (tid == 0) {
            __hip_atomic_fetch_add(&ctrs[step], 1u, __ATOMIC_RELAXED, __HIP_MEMORY_SCOPE_AGENT);
            int spins = 0;
            while (__hip_atomic_fetch_add(&ctrs[step], 0u, __ATOMIC_RELAXED, __HIP_MEMORY_SCOPE_AGENT) < NBLK) {
                __builtin_amdgcn_s_sleep(2);
                if (++spins > (1<<20)) break;   // safety valve (pacing only)
            }
        }
        __syncthreads();
    }
}

// transpose + split-cast: in (rows=[rowOff..rowOff+Kd) x N f32) -> out [N][Kd] hi/lo
__global__ __launch_bounds__(256) void tcast_k(
    const float* __restrict__ in, int rowOff, int Kd, int N,
    unsigned short* __restrict__ outH, unsigned short* __restrict__ outL)
{
    __shared__ float tl[32][33];
    const int kb = blockIdx.x*32, nb = blockIdx.y*32;
    const int tx = threadIdx.x, ty = threadIdx.y;
    for (int r = ty; r < 32; r += 8)
        tl[r][tx] = in[(size_t)(rowOff + kb + r)*N + nb + tx];
    __syncthreads();
    for (int r = ty; r < 32; r += 8) {
        unsigned short h, lo; f2b2(tl[tx][r], h, lo);
        size_t o = (size_t)(nb + r)*Kd + kb + tx;
        outH[o] = h; outL[o] = lo;
    }
}

__global__ __launch_bounds__(128) void encoder_k(
    const float* __restrict__ x,
    const float* __restrict__ w1, const float* __restrict__ b1,
    const float* __restrict__ w2, const float* __restrict__ b2,
    float* __restrict__ y0)
{
    int b = blockIdx.x;
    __shared__ float h[H_];
    int tid = threadIdx.x;
    float x0 = x[b*3+0], x1 = x[b*3+1], x2 = x[b*3+2];
    for (int i = tid; i < H_; i += 128)
        h[i] = fmaxf(x0*w1[i] + x1*w1[H_+i] + x2*w1[2*H_+i] + b1[i], 0.f);
    __syncthreads();
    float acc = b2[tid];
    for (int k = 0; k < H_; ++k) acc += h[k]*w2[k*S_+tid];
    y0[(size_t)b*S_ + tid] = acc;
}

__global__ void zero_ctr_k(unsigned int* c) { c[threadIdx.x] = 0; }

extern "C" void kernel_launch(void* const* d_in, const int* in_sizes, int n_in,
                              void* d_out, int out_size, void* d_ws, size_t ws_size,
                              hipStream_t stream)
{
    const float* ts     = (const float*)d_in[0];
    const float* x      = (const float*)d_in[1];
    const float* enc_w1 = (const float*)d_in[2];
    const float* enc_b1 = (const float*)d_in[3];
    const float* enc_w2 = (const float*)d_in[4];
    const float* enc_b2 = (const float*)d_in[5];
    const float* f_w1   = (const float*)d_in[6];
    const float* f_b1   = (const float*)d_in[7];
    const float* f_w2   = (const float*)d_in[8];
    const float* f_b2   = (const float*)d_in[9];
    const float* f_w3   = (const float*)d_in[10];
    const float* f_b3   = (const float*)d_in[11];
    const float* g_w1   = (const float*)d_in[12];
    const float* g_b1   = (const float*)d_in[13];
    const float* g_w2   = (const float*)d_in[14];
    const float* g_b2   = (const float*)d_in[15];
    const float* dW     = (const float*)d_in[16];

    float* out = (float*)d_out;
    unsigned short* wsp = (unsigned short*)d_ws;

    unsigned short* w1tH = wsp;                     // [1024][128]
    unsigned short* w1tL = w1tH + 1024*128;
    unsigned short* gw2H = w1tL + 1024*128;         // [2048][512]
    unsigned short* gw2L = gw2H + 2048*512;
    unsigned short* fw2H = gw2L + 2048*512;         // [512][512]
    unsigned short* fw2L = fw2H + 512*512;
    unsigned short* fw3H = fw2L + 512*512;          // [128][512]
    unsigned short* fw3L = fw3H + 128*512;
    unsigned int*   ctrs = (unsigned int*)(fw3L + 128*512);  // 64 uints

    dim3 tb(32,8);
    tcast_k<<<dim3(4,16),  tb, 0, stream>>>(g_w1, 1, 128, 512,  w1tH,         w1tL);
    tcast_k<<<dim3(4,16),  tb, 0, stream>>>(f_w1, 1, 128, 512,  w1tH+512*128, w1tL+512*128);
    tcast_k<<<dim3(16,16), tb, 0, stream>>>(f_w2, 0, 512, 512,  fw2H,         fw2L);
    tcast_k<<<dim3(16,4),  tb, 0, stream>>>(f_w3, 0, 512, 128,  fw3H,         fw3L);
    tcast_k<<<dim3(16,64), tb, 0, stream>>>(g_w2, 0, 512, 2048, gw2H,         gw2L);

    encoder_k<<<B_, 128, 0, stream>>>(x, enc_w1, enc_b1, enc_w2, enc_b2, out);
    zero_ctr_k<<<1, 64, 0, stream>>>(ctrs);

    sde_k<<<NBLK, THREADS, 0, stream>>>(
        ts, dW, g_w1, g_b1, f_w1, f_b1, f_b2, f_b3, g_b2,
        w1tH, w1tL, gw2H, gw2L, fw2H, fw2L, fw3H, fw3L,
        out, ctrs);
}